// Round 4
// baseline (457.275 us; speedup 1.0000x reference)
//
#include <hip/hip_runtime.h>
#include <hip/hip_bf16.h>

#define NPIX 4096
#define CCH  256
#define HID  64
#define BAT  4
#define XSTR 264   // proj LDS row stride (halfs)

using f32x4 = __attribute__((ext_vector_type(4))) float;
using h16x8 = __attribute__((ext_vector_type(8))) _Float16;
using u16x4 = __attribute__((ext_vector_type(4))) unsigned short;

__device__ __forceinline__ unsigned short f2h(float f) {
    _Float16 h = (_Float16)f;
    return __builtin_bit_cast(unsigned short, h);
}
__device__ __forceinline__ float h2f(unsigned short u) {
    return (float)__builtin_bit_cast(_Float16, u);
}
__device__ __forceinline__ h16x8 ldg_frag(const unsigned short* p) {
    uint4 v = *reinterpret_cast<const uint4*>(p);
    return __builtin_bit_cast(h16x8, v);
}
__device__ __forceinline__ h16x8 lds_frag(const unsigned short* p) {
    return *reinterpret_cast<const h16x8*>(p);
}
// order-preserving float<->uint encoding
__device__ __forceinline__ unsigned int encf(float f) {
    unsigned int u = __builtin_bit_cast(unsigned int, f);
    return (u & 0x80000000u) ? ~u : (u | 0x80000000u);
}
__device__ __forceinline__ float decf(unsigned int e) {
    unsigned int u = (e & 0x80000000u) ? (e ^ 0x80000000u) : ~e;
    return __builtin_bit_cast(float, u);
}
__device__ __forceinline__ float sel4(float a0, float a1, float a2, float a3, int q) {
    float x = (q & 1) ? a1 : a0;
    float y = (q & 1) ? a3 : a2;
    return (q & 2) ? y : x;
}

// ---------------------------------------------------------------------------
// W conversion: Wq/Wk/Wv fp32 -> row-major [384][256] fp16 (no split needed).
// ---------------------------------------------------------------------------
__global__ __launch_bounds__(256, 1) void wcvt_kernel(
    const float* __restrict__ Wq, const float* __restrict__ Wk,
    const float* __restrict__ Wv, unsigned short* __restrict__ Wg)
{
    int idx = (blockIdx.x * 256 + threadIdx.x) * 4;   // 98304 elems
    int r = idx >> 8, c = idx & 255;
    const float* src = (r < 64)  ? (Wq + r * CCH + c)
                     : (r < 128) ? (Wk + (r - 64) * CCH + c)
                                 : (Wv + (r - 128) * CCH + c);
    float4 v4 = *reinterpret_cast<const float4*>(src);
    u16x4 hv;
    hv[0] = f2h(v4.x); hv[1] = f2h(v4.y); hv[2] = f2h(v4.z); hv[3] = f2h(v4.w);
    *reinterpret_cast<u16x4*>(Wg + idx) = hv;
}

// ---------------------------------------------------------------------------
// fp16 MFMA projection. Block = (s, b, 32-pixel tile). x^T fp16 in LDS;
// x-fragments hoisted to registers ONCE and reused across all 6 htiles.
// Single fp16 MFMA per product (no split): rel err ~5e-4.
//  - V:   D[c][n] = mfma(Wfrag, xfrag) -> Vt [c][n]
//  - Q/K: D[n][h] = mfma(xfrag, Wfrag) -> [n][h]
// ---------------------------------------------------------------------------
__global__ __launch_bounds__(256, 3) void proj_kernel(
    const float* __restrict__ x1, const float* __restrict__ x2,
    const unsigned short* __restrict__ Wg,
    const float* __restrict__ bq, const float* __restrict__ bk,
    const float* __restrict__ bv,
    unsigned short* __restrict__ Qf, unsigned short* __restrict__ Kf,
    unsigned short* __restrict__ Vt)
{
    __shared__ unsigned short xs[32][XSTR];

    const int Lb = blockIdx.x;
    const int sb = Lb & 7;              // XCD-locality swizzle
    const int tile = Lb >> 3;
    const int s = sb >> 2, b = sb & 3;
    const float* x = s ? x2 : x1;
    const int n0 = tile * 32;
    const int t = threadIdx.x;
    const int lane = t & 63;
    const int w = __builtin_amdgcn_readfirstlane(t >> 6);
    const int quad = lane >> 4, lq = lane & 15;

    // stage x^T fp16 into LDS
    {
        const int n = t & 31;
        const int g = t >> 5;
        const float* xb = x + (size_t)(b * CCH) * NPIX + n0;
        #pragma unroll
        for (int i = 0; i < 8; ++i) {
            int c0 = g * 4 + i * 32;
            u16x4 hv;
            #pragma unroll
            for (int j = 0; j < 4; ++j)
                hv[j] = f2h(xb[(size_t)(c0 + j) * NPIX + n]);
            *reinterpret_cast<u16x4*>(&xs[n][c0]) = hv;
        }
    }
    __syncthreads();

    // hoist x fragments (both ntiles, full K=256): 16 frags = 64 VGPR
    h16x8 xf[2][8];
    #pragma unroll
    for (int nt = 0; nt < 2; ++nt)
        #pragma unroll
        for (int ks = 0; ks < 8; ++ks)
            xf[nt][ks] = lds_frag(&xs[nt * 16 + lq][ks * 32 + quad * 8]);

    const int sbN = (s * BAT + b) * NPIX;
    const int sbC = (s * BAT + b) * CCH;

    for (int hloop = 0; hloop < 6; ++hloop) {
        const int idx = w * 6 + hloop;                  // wave-uniform, 0..23
        const int kind = idx < 4 ? 0 : (idx < 8 ? 1 : 2);

        h16x8 wf[8];
        const unsigned short* wp = Wg + (size_t)(idx * 16 + lq) * CCH + quad * 8;
        #pragma unroll
        for (int ks = 0; ks < 8; ++ks) wf[ks] = ldg_frag(wp + ks * 32);

        #pragma unroll
        for (int nt = 0; nt < 2; ++nt) {
            f32x4 acc = (f32x4){0.f, 0.f, 0.f, 0.f};
            if (kind == 2) {
                #pragma unroll
                for (int ks = 0; ks < 8; ++ks)
                    acc = __builtin_amdgcn_mfma_f32_16x16x32_f16(wf[ks], xf[nt][ks], acc, 0, 0, 0);
                int cbase = (idx - 8) * 16 + quad * 4;
                int nn = n0 + nt * 16 + lq;
                #pragma unroll
                for (int reg = 0; reg < 4; ++reg) {
                    int c = cbase + reg;
                    Vt[(size_t)(sbC + c) * NPIX + nn] = f2h(acc[reg] + bv[c]);
                }
            } else {
                #pragma unroll
                for (int ks = 0; ks < 8; ++ks)
                    acc = __builtin_amdgcn_mfma_f32_16x16x32_f16(xf[nt][ks], wf[ks], acc, 0, 0, 0);
                unsigned short* dq = (kind ? Kf : Qf);
                const float* bias = (kind ? bk : bq);
                int hl = (kind ? (idx - 4) : idx) * 16 + lq;
                float bb = bias[hl];
                #pragma unroll
                for (int reg = 0; reg < 4; ++reg) {
                    int nn = n0 + nt * 16 + quad * 4 + reg;
                    dq[(size_t)(sbN + nn) * HID + hl] = f2h(acc[reg] + bb);
                }
            }
        }
    }
}

// ---------------------------------------------------------------------------
// Flash cross-attention v4: fp16, grid m-split (half = m 0..2047 / 2048..4095).
// Each block: 32 iters of 64 m. Emits UNNORMALIZED partial O (half0 -> d_out
// fp32, half1 -> ws fp16) plus per-column M (running max) and L (sum).
// Merge kernel combines.
// ---------------------------------------------------------------------------
__global__ __launch_bounds__(256, 3) void attn_kernel(
    const unsigned short* __restrict__ Qf, const unsigned short* __restrict__ Kf,
    const unsigned short* __restrict__ Vt,
    float* __restrict__ O0, unsigned short* __restrict__ O1,
    float* __restrict__ Mp, float* __restrict__ Lp)
{
    __shared__ unsigned short PT[64 * 72];   // P^T [n][m], +8 pad (fp16)
    __shared__ unsigned int pmaxI[64];
    __shared__ float Lsh[4][64];

    const int Lb = blockIdx.x;
    const int g = Lb & 7;                    // XCD-locality swizzle
    const int ntile = (Lb >> 3) & 63;
    const int half = Lb >> 9;                // m-half
    const int d = g >> 2, b = g & 3;
    const int db = d * BAT + b;
    const int s = d, r = 1 - d;
    const int n0 = ntile * 64;
    const int mb = half * 2048;

    const int t = threadIdx.x;
    const int lane = t & 63;
    const int w = __builtin_amdgcn_readfirstlane(t >> 6);
    const int quad = lane >> 4, lq = lane & 15;

    const unsigned short* Qb = Qf + (size_t)(s * BAT + b) * NPIX * HID;
    const unsigned short* Kb = Kf + (size_t)(r * BAT + b) * NPIX * HID;
    const unsigned short* Vb = Vt + (size_t)(r * BAT + b) * CCH * NPIX;

    if (t < 64) pmaxI[t] = 0x007FFFFFu;      // enc(-inf)

    // Q fragments, persistent
    h16x8 qf[4][2];
    #pragma unroll
    for (int nt = 0; nt < 4; ++nt)
        #pragma unroll
        for (int ks = 0; ks < 2; ++ks)
            qf[nt][ks] = ldg_frag(Qb + (n0 + nt * 16 + lq) * HID + ks * 32 + quad * 8);

    f32x4 Oacc[4][4];
    #pragma unroll
    for (int rt = 0; rt < 4; ++rt)
        #pragma unroll
        for (int ct = 0; ct < 4; ++ct)
            Oacc[rt][ct] = (f32x4){0.f, 0.f, 0.f, 0.f};

    float Mi[4], Li[4];
    #pragma unroll
    for (int nt = 0; nt < 4; ++nt) { Mi[nt] = -3.0e38f; Li[nt] = 0.f; }

    // K(0), V(0) fragments
    h16x8 kf[2], vf[4][2];
    {
        int ko = (mb + w * 16 + lq) * HID + quad * 8;
        kf[0] = ldg_frag(Kb + ko);  kf[1] = ldg_frag(Kb + ko + 32);
        #pragma unroll
        for (int rt = 0; rt < 4; ++rt)
            #pragma unroll
            for (int ks = 0; ks < 2; ++ks)
                vf[rt][ks] = ldg_frag(Vb + (size_t)(w * 64 + rt * 16 + lq) * NPIX
                                         + mb + ks * 32 + quad * 8);
    }
    __syncthreads();   // pmaxI init visible

    f32x4 Sacc[4];

    // ---- S(0) ----
    #pragma unroll
    for (int nt = 0; nt < 4; ++nt) Sacc[nt] = (f32x4){0.f, 0.f, 0.f, 0.f};
    #pragma unroll
    for (int ks = 0; ks < 2; ++ks)
        #pragma unroll
        for (int nt = 0; nt < 4; ++nt)
            Sacc[nt] = __builtin_amdgcn_mfma_f32_16x16x32_f16(kf[ks], qf[nt][ks], Sacc[nt], 0, 0, 0);
    // prefetch K(1)
    {
        int ko = (mb + 64 + w * 16 + lq) * HID + quad * 8;
        kf[0] = ldg_frag(Kb + ko);  kf[1] = ldg_frag(Kb + ko + 32);
    }
    // ---- phase1(0) ----
    {
        float pm[4];
        #pragma unroll
        for (int nt = 0; nt < 4; ++nt) {
            float p = fmaxf(fmaxf(Sacc[nt][0], Sacc[nt][1]),
                            fmaxf(Sacc[nt][2], Sacc[nt][3]));
            p = fmaxf(p, __shfl_xor(p, 16));
            p = fmaxf(p, __shfl_xor(p, 32));
            pm[nt] = p;
        }
        atomicMax(&pmaxI[quad * 16 + lq], encf(sel4(pm[0], pm[1], pm[2], pm[3], quad)));
    }
    __syncthreads();   // B1

    for (int it = 0; it < 32; ++it) {
        // ---- phase2(it) ----
        {
            float Mn[4];
            bool chg = false;
            #pragma unroll
            for (int nt = 0; nt < 4; ++nt) {
                float mv = decf(pmaxI[nt * 16 + lq]);
                Mn[nt] = fmaxf(Mi[nt], mv);
                chg = chg || (Mn[nt] > Mi[nt]);
            }
            if (__ballot(chg)) {
                float al[4];
                #pragma unroll
                for (int nt = 0; nt < 4; ++nt) {
                    al[nt] = __expf(Mi[nt] - Mn[nt]);
                    Li[nt] *= al[nt];
                }
                #pragma unroll
                for (int rt = 0; rt < 4; ++rt)
                    #pragma unroll
                    for (int ct = 0; ct < 4; ++ct)
                        Oacc[rt][ct] *= al[ct];
            }
            #pragma unroll
            for (int nt = 0; nt < 4; ++nt) {
                Mi[nt] = Mn[nt];
                float p0 = __expf(Sacc[nt][0] - Mn[nt]);
                float p1 = __expf(Sacc[nt][1] - Mn[nt]);
                float p2 = __expf(Sacc[nt][2] - Mn[nt]);
                float p3 = __expf(Sacc[nt][3] - Mn[nt]);
                float ps = (p0 + p1) + (p2 + p3);
                ps += __shfl_xor(ps, 16);
                ps += __shfl_xor(ps, 32);
                Li[nt] += ps;
                u16x4 pk;
                pk[0] = f2h(p0); pk[1] = f2h(p1); pk[2] = f2h(p2); pk[3] = f2h(p3);
                *reinterpret_cast<u16x4*>(&PT[(nt * 16 + lq) * 72 + w * 16 + quad * 4]) = pk;
            }
        }
        __syncthreads();   // B2: PT(it) visible

        // ---- PV(it) ----
        #pragma unroll
        for (int ks = 0; ks < 2; ++ks) {
            h16x8 pf[4];
            #pragma unroll
            for (int ct = 0; ct < 4; ++ct)
                pf[ct] = lds_frag(&PT[(ct * 16 + lq) * 72 + ks * 32 + quad * 8]);
            #pragma unroll
            for (int rt = 0; rt < 4; ++rt)
                #pragma unroll
                for (int ct = 0; ct < 4; ++ct)
                    Oacc[rt][ct] = __builtin_amdgcn_mfma_f32_16x16x32_f16(
                        vf[rt][ks], pf[ct], Oacc[rt][ct], 0, 0, 0);
        }
        // prefetch V(it+1)
        const int itv = (it < 31) ? it + 1 : 31;
        #pragma unroll
        for (int rt = 0; rt < 4; ++rt)
            #pragma unroll
            for (int ks = 0; ks < 2; ++ks)
                vf[rt][ks] = ldg_frag(Vb + (size_t)(w * 64 + rt * 16 + lq) * NPIX
                                         + mb + itv * 64 + ks * 32 + quad * 8);

        // ---- S(it+1) ----  (last iter recomputes S(31): max is idempotent)
        #pragma unroll
        for (int nt = 0; nt < 4; ++nt) Sacc[nt] = (f32x4){0.f, 0.f, 0.f, 0.f};
        #pragma unroll
        for (int ks = 0; ks < 2; ++ks)
            #pragma unroll
            for (int nt = 0; nt < 4; ++nt)
                Sacc[nt] = __builtin_amdgcn_mfma_f32_16x16x32_f16(kf[ks], qf[nt][ks], Sacc[nt], 0, 0, 0);
        // prefetch K(it+2)
        const int itk = (it < 30) ? it + 2 : 31;
        {
            int ko = (mb + itk * 64 + w * 16 + lq) * HID + quad * 8;
            kf[0] = ldg_frag(Kb + ko);  kf[1] = ldg_frag(Kb + ko + 32);
        }
        // ---- phase1(it+1) ----
        {
            float pm[4];
            #pragma unroll
            for (int nt = 0; nt < 4; ++nt) {
                float p = fmaxf(fmaxf(Sacc[nt][0], Sacc[nt][1]),
                                fmaxf(Sacc[nt][2], Sacc[nt][3]));
                p = fmaxf(p, __shfl_xor(p, 16));
                p = fmaxf(p, __shfl_xor(p, 32));
                pm[nt] = p;
            }
            atomicMax(&pmaxI[quad * 16 + lq], encf(sel4(pm[0], pm[1], pm[2], pm[3], quad)));
        }
        __syncthreads();   // B1
    }

    // ---- epilogue: store unnormalized partial O, and M/L per column ----
    Lsh[w][quad * 16 + lq] = sel4(Li[0], Li[1], Li[2], Li[3], quad);
    __syncthreads();

    #pragma unroll
    for (int rt = 0; rt < 4; ++rt)
        #pragma unroll
        for (int ct = 0; ct < 4; ++ct)
            #pragma unroll
            for (int rg = 0; rg < 4; ++rg) {
                int c = w * 64 + rt * 16 + quad * 4 + rg;
                int nn = n0 + ct * 16 + lq;
                size_t dst = (size_t)(db * CCH + c) * NPIX + nn;
                if (half == 0) O0[dst] = Oacc[rt][ct][rg];
                else           O1[dst] = f2h(Oacc[rt][ct][rg]);
            }

    if (w == 0 && quad == 0) {
        #pragma unroll
        for (int nt = 0; nt < 4; ++nt) {
            int i = nt * 16 + lq;
            float Lt = (Lsh[0][i] + Lsh[1][i]) + (Lsh[2][i] + Lsh[3][i]);
            size_t mi = (size_t)(half * 8 + db) * NPIX + n0 + i;
            Mp[mi] = Mi[nt];
            Lp[mi] = Lt;
        }
    }
}

// ---------------------------------------------------------------------------
// Merge: out = xq + gamma * (a0*O0 + a1*O1) / (a0*L0 + a1*L1),
// a_h = exp(M_h - max(M0,M1)). O0 lives in d_out (read-modify-write).
// ---------------------------------------------------------------------------
__global__ __launch_bounds__(256, 4) void merge_kernel(
    const float* __restrict__ x1, const float* __restrict__ x2,
    const unsigned short* __restrict__ O1,
    const float* __restrict__ Mp, const float* __restrict__ Lp,
    const float* __restrict__ gamma,
    float* __restrict__ out)
{
    const int i = (blockIdx.x * 256 + threadIdx.x) * 4;   // 8,388,608 floats
    const int db = i >> 20;                               // /(256*4096)
    const int n = i & (NPIX - 1);
    const float gm = gamma[0];

    f32x4 m0 = *reinterpret_cast<const f32x4*>(&Mp[(size_t)db * NPIX + n]);
    f32x4 m1 = *reinterpret_cast<const f32x4*>(&Mp[(size_t)(8 + db) * NPIX + n]);
    f32x4 l0 = *reinterpret_cast<const f32x4*>(&Lp[(size_t)db * NPIX + n]);
    f32x4 l1 = *reinterpret_cast<const f32x4*>(&Lp[(size_t)(8 + db) * NPIX + n]);
    f32x4 o0 = *reinterpret_cast<const f32x4*>(&out[i]);
    u16x4 o1u = *reinterpret_cast<const u16x4*>(&O1[i]);
    const float* xq = (db >= 4) ? x2 : x1;
    f32x4 xv = *reinterpret_cast<const f32x4*>(&xq[i - (db >= 4 ? 4194304 : 0)]);

    f32x4 res;
    #pragma unroll
    for (int j = 0; j < 4; ++j) {
        float M  = fmaxf(m0[j], m1[j]);
        float a0 = __expf(m0[j] - M);
        float a1 = __expf(m1[j] - M);
        float L  = a0 * l0[j] + a1 * l1[j];
        res[j] = xv[j] + gm * (a0 * o0[j] + a1 * h2f(o1u[j])) / L;
    }
    *reinterpret_cast<f32x4*>(&out[i]) = res;
}

// ---------------------------------------------------------------------------
extern "C" void kernel_launch(void* const* d_in, const int* in_sizes, int n_in,
                              void* d_out, int out_size, void* d_ws, size_t ws_size,
                              hipStream_t stream) {
    (void)in_sizes; (void)n_in; (void)out_size; (void)ws_size;
    const float* x1 = (const float*)d_in[0];
    const float* x2 = (const float*)d_in[1];
    const float* Wq = (const float*)d_in[2];
    const float* bq = (const float*)d_in[3];
    const float* Wk = (const float*)d_in[4];
    const float* bk = (const float*)d_in[5];
    const float* Wv = (const float*)d_in[6];
    const float* bv = (const float*)d_in[7];
    const float* gm = (const float*)d_in[8];
    float* out = (float*)d_out;

    // ws layout (fp16 elems): Qf 2.1M | Kf 2.1M | Vt 8.4M | O1 8.4M | Wg 98304
    // then fp32: Mp 65536 | Lp 65536.  Total ~42.7 MB.
    unsigned short* ws = (unsigned short*)d_ws;
    unsigned short* Qf = ws;
    unsigned short* Kf = Qf + (size_t)2097152;
    unsigned short* Vt = Kf + (size_t)2097152;
    unsigned short* O1 = Vt + (size_t)8388608;
    unsigned short* Wg = O1 + (size_t)8388608;
    float* ML = (float*)(Wg + 98304);
    float* Mp = ML;
    float* Lp = ML + 65536;

    wcvt_kernel<<<dim3(96), dim3(256), 0, stream>>>(Wq, Wk, Wv, Wg);
    proj_kernel<<<dim3(1024), dim3(256), 0, stream>>>(
        x1, x2, Wg, bq, bk, bv, Qf, Kf, Vt);
    attn_kernel<<<dim3(1024), dim3(256), 0, stream>>>(
        Qf, Kf, Vt, out, O1, Mp, Lp);
    merge_kernel<<<dim3(8192), dim3(256), 0, stream>>>(
        x1, x2, O1, Mp, Lp, gm, out);
}

// Round 5
// 323.187 us; speedup vs baseline: 1.4149x; 1.4149x over previous
//
#include <hip/hip_runtime.h>
#include <hip/hip_bf16.h>

#define NPIX 4096
#define CCH  256
#define HID  64
#define BAT  4
#define XSTR 264    // proj LDS row stride (halfs)
#define PTSTR 268   // attn P-tile row stride (halfs): 8B-aligned rows, ~2-way banks

using f32x4 = __attribute__((ext_vector_type(4))) float;
using h16x8 = __attribute__((ext_vector_type(8))) _Float16;
using u16x4 = __attribute__((ext_vector_type(4))) unsigned short;

#define L2E 1.44269504088896340736f

__device__ __forceinline__ unsigned short f2h(float f) {
    _Float16 h = (_Float16)f;
    return __builtin_bit_cast(unsigned short, h);
}
__device__ __forceinline__ h16x8 ldg_frag(const unsigned short* p) {
    uint4 v = *reinterpret_cast<const uint4*>(p);
    return __builtin_bit_cast(h16x8, v);
}
__device__ __forceinline__ h16x8 lds_frag(const unsigned short* p) {
    return *reinterpret_cast<const h16x8*>(p);
}
__device__ __forceinline__ unsigned int pk2h(float a, float b) {
    auto t = __builtin_amdgcn_cvt_pkrtz(a, b);   // <2 x half>, RTZ
    return __builtin_bit_cast(unsigned int, t);
}
// order-preserving float<->uint encoding (unsigned max == float max)
__device__ __forceinline__ unsigned int encf(float f) {
    unsigned int u = __builtin_bit_cast(unsigned int, f);
    return (u & 0x80000000u) ? ~u : (u | 0x80000000u);
}
__device__ __forceinline__ float decf(unsigned int e) {
    unsigned int u = (e & 0x80000000u) ? (e ^ 0x80000000u) : ~e;
    return __builtin_bit_cast(float, u);
}
__device__ __forceinline__ float sel4(float a0, float a1, float a2, float a3, int q) {
    float x = (q & 1) ? a1 : a0;
    float y = (q & 1) ? a3 : a2;
    return (q & 2) ? y : x;
}

// ---------------------------------------------------------------------------
// W conversion -> row-major [384][256] fp16. Rows 0-63: Wq (pre-scaled by
// log2(e) so attention can use exp2), 64-127: Wk, 128-383: Wv.
// ---------------------------------------------------------------------------
__global__ __launch_bounds__(256, 1) void wcvt_kernel(
    const float* __restrict__ Wq, const float* __restrict__ Wk,
    const float* __restrict__ Wv, unsigned short* __restrict__ Wg)
{
    int idx = (blockIdx.x * 256 + threadIdx.x) * 4;
    int r = idx >> 8, c = idx & 255;
    const float* src = (r < 64)  ? (Wq + r * CCH + c)
                     : (r < 128) ? (Wk + (r - 64) * CCH + c)
                                 : (Wv + (r - 128) * CCH + c);
    float sc = (r < 64) ? L2E : 1.0f;
    float4 v4 = *reinterpret_cast<const float4*>(src);
    u16x4 hv;
    hv[0] = f2h(v4.x * sc); hv[1] = f2h(v4.y * sc);
    hv[2] = f2h(v4.z * sc); hv[3] = f2h(v4.w * sc);
    *reinterpret_cast<u16x4*>(Wg + idx) = hv;
}

// ---------------------------------------------------------------------------
// fp16 MFMA projection. Block = (s, b, 32-pixel tile). x^T fp16 in LDS,
// x-frags hoisted to registers. Epilogue round-trips each 16x16 D-tile
// through per-wave LDS scratch (intra-wave, no barrier) so global stores are
// coalesced b64 instead of scattered 2B.
// ---------------------------------------------------------------------------
__global__ __launch_bounds__(256, 2) void proj_kernel(
    const float* __restrict__ x1, const float* __restrict__ x2,
    const unsigned short* __restrict__ Wg,
    const float* __restrict__ bq, const float* __restrict__ bk,
    const float* __restrict__ bv,
    unsigned short* __restrict__ Qf, unsigned short* __restrict__ Kf,
    unsigned short* __restrict__ Vt)
{
    __shared__ unsigned short xs[32][XSTR];
    __shared__ unsigned short scratch[4][256];   // per-wave 16x16 tile

    const int Lb = blockIdx.x;
    const int sb = Lb & 7;              // XCD-locality swizzle
    const int tile = Lb >> 3;
    const int s = sb >> 2, b = sb & 3;
    const float* x = s ? x2 : x1;
    const int n0 = tile * 32;
    const int t = threadIdx.x;
    const int lane = t & 63;
    const int w = __builtin_amdgcn_readfirstlane(t >> 6);
    const int quad = lane >> 4, lq = lane & 15;

    // stage x^T fp16 into LDS
    {
        const int n = t & 31;
        const int g = t >> 5;
        const float* xb = x + (size_t)(b * CCH) * NPIX + n0;
        #pragma unroll
        for (int i = 0; i < 8; ++i) {
            int c0 = g * 4 + i * 32;
            u16x4 hv;
            #pragma unroll
            for (int j = 0; j < 4; ++j)
                hv[j] = f2h(xb[(size_t)(c0 + j) * NPIX + n]);
            *reinterpret_cast<u16x4*>(&xs[n][c0]) = hv;
        }
    }
    __syncthreads();

    // hoist x fragments (both ntiles, full K=256)
    h16x8 xf[2][8];
    #pragma unroll
    for (int nt = 0; nt < 2; ++nt)
        #pragma unroll
        for (int ks = 0; ks < 8; ++ks)
            xf[nt][ks] = lds_frag(&xs[nt * 16 + lq][ks * 32 + quad * 8]);
    __syncthreads();   // xs free for... (scratch is separate; barrier for safety of xs reuse semantics)

    const int sbN = (s * BAT + b) * NPIX;
    const int sbC = (s * BAT + b) * CCH;
    unsigned short* sc = scratch[w];

    for (int hloop = 0; hloop < 6; ++hloop) {
        const int idx = w * 6 + hloop;                  // wave-uniform, 0..23
        const int kind = idx < 4 ? 0 : (idx < 8 ? 1 : 2);

        h16x8 wf[8];
        const unsigned short* wp = Wg + (size_t)(idx * 16 + lq) * CCH + quad * 8;
        #pragma unroll
        for (int ks = 0; ks < 8; ++ks) wf[ks] = ldg_frag(wp + ks * 32);

        #pragma unroll
        for (int nt = 0; nt < 2; ++nt) {
            f32x4 acc = (f32x4){0.f, 0.f, 0.f, 0.f};
            if (kind == 2) {
                #pragma unroll
                for (int ks = 0; ks < 8; ++ks)
                    acc = __builtin_amdgcn_mfma_f32_16x16x32_f16(wf[ks], xf[nt][ks], acc, 0, 0, 0);
                // D[c][n]: c_local = quad*4+reg, n_local = lq
                int cbase = (idx - 8) * 16;
                float bb = bv[cbase + quad * 4];   // per-reg bias added below
                (void)bb;
                #pragma unroll
                for (int reg = 0; reg < 4; ++reg)
                    sc[(quad * 4 + reg) * 16 + lq] = f2h(acc[reg] + bv[cbase + quad * 4 + reg]);
                // coalesced store: lane -> row lane>>2, 4 cols (lane&3)*4
                int rl = lane >> 2, c0 = (lane & 3) * 4;
                __builtin_amdgcn_s_waitcnt(0);  // lgkm drain for scratch (compiler also tracks)
                unsigned long long v = *reinterpret_cast<const unsigned long long*>(&sc[rl * 16 + c0]);
                *reinterpret_cast<unsigned long long*>(
                    &Vt[(size_t)(sbC + cbase + rl) * NPIX + n0 + nt * 16 + c0]) = v;
            } else {
                #pragma unroll
                for (int ks = 0; ks < 8; ++ks)
                    acc = __builtin_amdgcn_mfma_f32_16x16x32_f16(xf[nt][ks], wf[ks], acc, 0, 0, 0);
                // D[n][h]: n_local = quad*4+reg, h_local = lq
                unsigned short* dq = (kind ? Kf : Qf);
                const float* bias = (kind ? bk : bq);
                int hbase = (kind ? (idx - 4) : idx) * 16;
                float bb = bias[hbase + lq];
                float scl = kind ? 1.0f : L2E;
                #pragma unroll
                for (int reg = 0; reg < 4; ++reg)
                    sc[(quad * 4 + reg) * 16 + lq] = f2h(acc[reg] + bb * scl);
                int rl = lane >> 2, h0 = (lane & 3) * 4;
                __builtin_amdgcn_s_waitcnt(0);
                unsigned long long v = *reinterpret_cast<const unsigned long long*>(&sc[rl * 16 + h0]);
                *reinterpret_cast<unsigned long long*>(
                    &dq[(size_t)(sbN + n0 + nt * 16 + rl) * HID + hbase + h0]) = v;
            }
        }
    }
}

// ---------------------------------------------------------------------------
// Flash cross-attention v5: 256-m mega-iterations (16 iters, 2 barriers each).
// Per iter per wave: S = K Q^T for its 64 m-rows (32 MFMA), softmax in log2
// units (exp2), P -> LDS (fp16), barrier, PV = V^T P^T (128 MFMA) with
// double-buffered V A-frags. Direct output write (no partials/merge).
// ---------------------------------------------------------------------------
__global__ __launch_bounds__(256, 2) void attn_kernel(
    const float* __restrict__ x1, const float* __restrict__ x2,
    const unsigned short* __restrict__ Qf, const unsigned short* __restrict__ Kf,
    const unsigned short* __restrict__ Vt,
    const float* __restrict__ gamma,
    float* __restrict__ out)
{
    __shared__ unsigned short PT[64 * PTSTR];   // P [n=64][m=256]
    __shared__ unsigned int pmaxI[64];          // running column max (encoded)
    __shared__ float Lsh[4][64];

    const int Lb = blockIdx.x;
    const int g = Lb & 7;                       // XCD-locality swizzle
    const int ntile = Lb >> 3;
    const int d = g >> 2, b = g & 3;
    const int db = d * BAT + b;
    const int s = d, r = 1 - d;
    const int n0 = ntile * 64;

    const int t = threadIdx.x;
    const int lane = t & 63;
    const int w = __builtin_amdgcn_readfirstlane(t >> 6);
    const int quad = lane >> 4, lq = lane & 15;

    const unsigned short* Qb = Qf + (size_t)(s * BAT + b) * NPIX * HID;
    const unsigned short* Kb = Kf + (size_t)(r * BAT + b) * NPIX * HID;
    const unsigned short* Vb = Vt + (size_t)(r * BAT + b) * CCH * NPIX;

    if (t < 64) pmaxI[t] = encf(-3.0e38f);

    // Q fragments, persistent (B-frags)
    h16x8 qf[4][2];
    #pragma unroll
    for (int nt = 0; nt < 4; ++nt)
        #pragma unroll
        for (int ks = 0; ks < 2; ++ks)
            qf[nt][ks] = ldg_frag(Qb + (n0 + nt * 16 + lq) * HID + ks * 32 + quad * 8);

    f32x4 Oacc[4][4];
    #pragma unroll
    for (int rt = 0; rt < 4; ++rt)
        #pragma unroll
        for (int ct = 0; ct < 4; ++ct)
            Oacc[rt][ct] = (f32x4){0.f, 0.f, 0.f, 0.f};

    float Mi[4], Li[4];
    #pragma unroll
    for (int nt = 0; nt < 4; ++nt) { Mi[nt] = -3.0e38f; Li[nt] = 0.f; }

    __syncthreads();   // pmaxI init visible

    for (int it = 0; it < 16; ++it) {
        const int m0 = it * 256;

        // ---- S phase: this wave's 64 m-rows x 64 n ----
        h16x8 kf[4][2];
        #pragma unroll
        for (int mt = 0; mt < 4; ++mt)
            #pragma unroll
            for (int ks = 0; ks < 2; ++ks)
                kf[mt][ks] = ldg_frag(Kb + (m0 + w * 64 + mt * 16 + lq) * HID
                                         + ks * 32 + quad * 8);
        f32x4 Sacc[4][4];
        #pragma unroll
        for (int mt = 0; mt < 4; ++mt)
            #pragma unroll
            for (int nt = 0; nt < 4; ++nt)
                Sacc[mt][nt] = (f32x4){0.f, 0.f, 0.f, 0.f};
        #pragma unroll
        for (int mt = 0; mt < 4; ++mt)
            #pragma unroll
            for (int ks = 0; ks < 2; ++ks)
                #pragma unroll
                for (int nt = 0; nt < 4; ++nt)
                    Sacc[mt][nt] = __builtin_amdgcn_mfma_f32_16x16x32_f16(
                        kf[mt][ks], qf[nt][ks], Sacc[mt][nt], 0, 0, 0);

        // phase1: column maxima of this wave's rows -> atomic LDS max
        {
            float cm[4];
            #pragma unroll
            for (int nt = 0; nt < 4; ++nt) {
                float p = -3.0e38f;
                #pragma unroll
                for (int mt = 0; mt < 4; ++mt)
                    p = fmaxf(p, fmaxf(fmaxf(Sacc[mt][nt][0], Sacc[mt][nt][1]),
                                       fmaxf(Sacc[mt][nt][2], Sacc[mt][nt][3])));
                p = fmaxf(p, __shfl_xor(p, 16));
                p = fmaxf(p, __shfl_xor(p, 32));
                cm[nt] = p;
            }
            atomicMax(&pmaxI[quad * 16 + lq], encf(sel4(cm[0], cm[1], cm[2], cm[3], quad)));
        }

        // prefetch V(ks=0) for the PV phase (drained by B2, hidden)
        h16x8 vfb[2][4];
        #pragma unroll
        for (int rt = 0; rt < 4; ++rt)
            vfb[0][rt] = ldg_frag(Vb + (size_t)(w * 64 + rt * 16 + lq) * NPIX
                                     + m0 + quad * 8);
        __syncthreads();   // B1: all maxima in

        // ---- phase2: exp2, P -> LDS, running M/L/O rescale ----
        {
            float Mn[4];
            bool chg = false;
            #pragma unroll
            for (int nt = 0; nt < 4; ++nt) {
                float mv = decf(pmaxI[nt * 16 + lq]);
                Mn[nt] = fmaxf(Mi[nt], mv);
                chg = chg || (Mn[nt] > Mi[nt]);
            }
            if (__ballot(chg)) {
                float al[4];
                #pragma unroll
                for (int nt = 0; nt < 4; ++nt) {
                    al[nt] = __builtin_amdgcn_exp2f(Mi[nt] - Mn[nt]);
                    Li[nt] *= al[nt];
                }
                #pragma unroll
                for (int rt = 0; rt < 4; ++rt)
                    #pragma unroll
                    for (int ct = 0; ct < 4; ++ct)
                        Oacc[rt][ct] *= al[ct];
            }
            #pragma unroll
            for (int nt = 0; nt < 4; ++nt) Mi[nt] = Mn[nt];
            #pragma unroll
            for (int mt = 0; mt < 4; ++mt)
                #pragma unroll
                for (int nt = 0; nt < 4; ++nt) {
                    float p0 = __builtin_amdgcn_exp2f(Sacc[mt][nt][0] - Mn[nt]);
                    float p1 = __builtin_amdgcn_exp2f(Sacc[mt][nt][1] - Mn[nt]);
                    float p2 = __builtin_amdgcn_exp2f(Sacc[mt][nt][2] - Mn[nt]);
                    float p3 = __builtin_amdgcn_exp2f(Sacc[mt][nt][3] - Mn[nt]);
                    Li[nt] += (p0 + p1) + (p2 + p3);
                    uint2 pk2;
                    pk2.x = pk2h(p0, p1);
                    pk2.y = pk2h(p2, p3);
                    *reinterpret_cast<uint2*>(
                        &PT[(nt * 16 + lq) * PTSTR + w * 64 + mt * 16 + quad * 4]) = pk2;
                }
        }
        __syncthreads();   // B2: P visible

        // ---- PV phase: O += V^T P^T over 256 m (8 k-chunks) ----
        #pragma unroll
        for (int ks = 0; ks < 8; ++ks) {
            h16x8 pf[4];
            #pragma unroll
            for (int ct = 0; ct < 4; ++ct)
                pf[ct] = lds_frag(&PT[(ct * 16 + lq) * PTSTR + ks * 32 + quad * 8]);
            if (ks < 7) {
                #pragma unroll
                for (int rt = 0; rt < 4; ++rt)
                    vfb[(ks + 1) & 1][rt] = ldg_frag(
                        Vb + (size_t)(w * 64 + rt * 16 + lq) * NPIX
                           + m0 + (ks + 1) * 32 + quad * 8);
            }
            #pragma unroll
            for (int rt = 0; rt < 4; ++rt)
                #pragma unroll
                for (int ct = 0; ct < 4; ++ct)
                    Oacc[rt][ct] = __builtin_amdgcn_mfma_f32_16x16x32_f16(
                        vfb[ks & 1][rt], pf[ct], Oacc[rt][ct], 0, 0, 0);
        }
    }

    // ---- epilogue: cross-quad + cross-wave L merge, write out ----
    #pragma unroll
    for (int nt = 0; nt < 4; ++nt) {
        Li[nt] += __shfl_xor(Li[nt], 16);
        Li[nt] += __shfl_xor(Li[nt], 32);
    }
    Lsh[w][quad * 16 + lq] = sel4(Li[0], Li[1], Li[2], Li[3], quad);
    __syncthreads();

    float inv[4];
    #pragma unroll
    for (int nt = 0; nt < 4; ++nt) {
        int i = nt * 16 + lq;
        inv[nt] = 1.0f / ((Lsh[0][i] + Lsh[1][i]) + (Lsh[2][i] + Lsh[3][i]));
    }

    const float* xq = d ? x2 : x1;
    const float gm = gamma[0];

    #pragma unroll
    for (int rt = 0; rt < 4; ++rt)
        #pragma unroll
        for (int ct = 0; ct < 4; ++ct)
            #pragma unroll
            for (int rg = 0; rg < 4; ++rg) {
                int c = w * 64 + rt * 16 + quad * 4 + rg;
                int nn = n0 + ct * 16 + lq;
                size_t src = (size_t)(b * CCH + c) * NPIX + nn;
                size_t dst = (size_t)(db * CCH + c) * NPIX + nn;
                out[dst] = xq[src] + gm * Oacc[rt][ct][rg] * inv[ct];
            }
}

// ---------------------------------------------------------------------------
extern "C" void kernel_launch(void* const* d_in, const int* in_sizes, int n_in,
                              void* d_out, int out_size, void* d_ws, size_t ws_size,
                              hipStream_t stream) {
    (void)in_sizes; (void)n_in; (void)out_size; (void)ws_size;
    const float* x1 = (const float*)d_in[0];
    const float* x2 = (const float*)d_in[1];
    const float* Wq = (const float*)d_in[2];
    const float* bq = (const float*)d_in[3];
    const float* Wk = (const float*)d_in[4];
    const float* bk = (const float*)d_in[5];
    const float* Wv = (const float*)d_in[6];
    const float* bv = (const float*)d_in[7];
    const float* gm = (const float*)d_in[8];
    float* out = (float*)d_out;

    // ws (fp16 elems): Qf 2.1M | Kf 2.1M | Vt 8.4M | Wg 98304  (~25.4 MB)
    unsigned short* ws = (unsigned short*)d_ws;
    unsigned short* Qf = ws;
    unsigned short* Kf = Qf + (size_t)2097152;
    unsigned short* Vt = Kf + (size_t)2097152;
    unsigned short* Wg = Vt + (size_t)8388608;

    wcvt_kernel<<<dim3(96), dim3(256), 0, stream>>>(Wq, Wk, Wv, Wg);
    proj_kernel<<<dim3(1024), dim3(256), 0, stream>>>(
        x1, x2, Wg, bq, bk, bv, Qf, Kf, Vt);
    attn_kernel<<<dim3(512), dim3(256), 0, stream>>>(
        x1, x2, Qf, Kf, Vt, gm, out);
}